// Round 1
// baseline (980.177 us; speedup 1.0000x reference)
//
#include <hip/hip_runtime.h>

// Problem constants (match reference setup_inputs)
#define NB 128
#define NL 512
#define NN 1023
#define NT 511
#define ND 256
#define NC 511
#define EPSF 1e-6f

typedef __attribute__((ext_vector_type(8))) short short8;   // 8 x bf16 (4 VGPRs)
typedef __attribute__((ext_vector_type(4))) float f32x4;    // MFMA accumulator

__device__ __forceinline__ unsigned short f2bf(float f) {
  unsigned u = __builtin_bit_cast(unsigned, f);
  u += 0x7FFFu + ((u >> 16) & 1u);   // round-to-nearest-even
  return (unsigned short)(u >> 16);
}

// ---------------------------------------------------------------------------
// Phase 1: scatter normalized embedding rows into vec[B,N,D] (vec pre-zeroed).
// One wave per (b,l) row; slots are unique per batch so no collisions.
// ---------------------------------------------------------------------------
__global__ void __launch_bounds__(256) embed_scatter(
    const int* __restrict__ lcid, const int* __restrict__ cmask,
    const float* __restrict__ emb, float* __restrict__ vec) {
  int rid  = blockIdx.x * 4 + (threadIdx.x >> 6);   // b*NL + l
  int lane = threadIdx.x & 63;
  if (cmask[rid] == 0) return;                       // row stays zero
  int node = lcid[2 * rid];
  int vid  = lcid[2 * rid + 1];
  int b    = rid >> 9;                               // / NL
  const float4* src = (const float4*)(emb + (size_t)vid * ND);
  float4 v = src[lane];                              // 64 lanes x 16B = 1KB row
  float ss = v.x * v.x + v.y * v.y + v.z * v.z + v.w * v.w;
#pragma unroll
  for (int off = 32; off > 0; off >>= 1) ss += __shfl_down(ss, off, 64);
  ss = __shfl(ss, 0, 64);
  float inv = 1.0f / (sqrtf(ss) + EPSF);
  float4 o;
  o.x = v.x * inv; o.y = v.y * inv; o.z = v.z * inv; o.w = v.w * inv;
  float4* dst = (float4*)(vec + ((size_t)b * NN + node) * ND);
  dst[lane] = o;
}

// ---------------------------------------------------------------------------
// Phase 2: compose scan. One block (256 threads, 4 waves) per batch; the 511
// steps are serial within the block, separated by __syncthreads(). Circular
// correlation computed directly: wave w covers j in [64w,64w+64), lane q owns
// outputs k=4q..4q+3 (rolling float4 window over a doubled b buffer), partials
// reduced across waves via LDS, then L2-normalized.
// ---------------------------------------------------------------------------
__global__ void __launch_bounds__(256) compose_kernel(
    const int* __restrict__ info, float* __restrict__ vec) {
  int b    = blockIdx.x;
  int tid  = threadIdx.x;
  int lane = tid & 63;
  int w    = tid >> 6;
  __shared__ int   sinfo[NT * 4];
  __shared__ float a_s[ND];
  __shared__ float b_s[2 * ND];
  __shared__ float part[4][ND];
  __shared__ float red[4];
  float* vb = vec + (size_t)b * NN * ND;
  const int* ib = info + b * NT * 4;
  for (int i = tid; i < NT * 4; i += 256) sinfo[i] = ib[i];
  __syncthreads();

  for (int t = 0; t < NT; ++t) {
    int ty = sinfo[4 * t + 0];
    int p  = sinfo[4 * t + 1];
    int lc = sinfo[4 * t + 2];
    int rc = sinfo[4 * t + 3];
    if (ty == 1) {
      // copy row lc -> row p (safe even if p==lc: identity write)
      float v = vb[lc * ND + tid];
      vb[p * ND + tid] = v;
      __syncthreads();
    } else if (ty == 2) {
      a_s[tid]      = vb[lc * ND + tid];
      float bv      = vb[rc * ND + tid];
      b_s[tid]      = bv;
      b_s[ND + tid] = bv;   // doubled for mod-256 window
      __syncthreads();
      const float4* a4 = (const float4*)a_s;
      const float4* b4 = (const float4*)b_s;
      float c0 = 0.f, c1 = 0.f, c2 = 0.f, c3 = 0.f;
      int base = 16 * w + lane;
      float4 B0 = b4[base];
#pragma unroll
      for (int i = 0; i < 16; ++i) {
        float4 A  = a4[16 * w + i];        // uniform -> LDS broadcast
        float4 B1 = b4[base + i + 1];      // rolling window
        c0 += A.x * B0.x + A.y * B0.y + A.z * B0.z + A.w * B0.w;
        c1 += A.x * B0.y + A.y * B0.z + A.z * B0.w + A.w * B1.x;
        c2 += A.x * B0.z + A.y * B0.w + A.z * B1.x + A.w * B1.y;
        c3 += A.x * B0.w + A.y * B1.x + A.z * B1.y + A.w * B1.z;
        B0 = B1;
      }
      float4 pc; pc.x = c0; pc.y = c1; pc.z = c2; pc.w = c3;
      ((float4*)part[w])[lane] = pc;
      __syncthreads();
      float c = part[0][tid] + part[1][tid] + part[2][tid] + part[3][tid];
      float ss = c * c;
#pragma unroll
      for (int off = 32; off > 0; off >>= 1) ss += __shfl_down(ss, off, 64);
      if (lane == 0) red[w] = ss;
      __syncthreads();
      float tot = red[0] + red[1] + red[2] + red[3];
      float inv = 1.0f / (sqrtf(tot) + EPSF);
      vb[p * ND + tid] = c * inv;
      __syncthreads();
    } else {
      __syncthreads();   // type 0: reference writes v[b,0]=v[b,0] (no-op)
    }
  }
}

// ---------------------------------------------------------------------------
// Phase 3a: fp32 -> bf16 conversions for the MFMA GEMM.
// ---------------------------------------------------------------------------
__global__ void __launch_bounds__(256) cvt_vec(
    const float* __restrict__ v, unsigned short* __restrict__ o, int n8) {
  int i = blockIdx.x * 256 + threadIdx.x;
  if (i >= n8) return;
  const float4* v4 = (const float4*)v;
  float4 x = v4[2 * i], y = v4[2 * i + 1];
  uint4 r;
  r.x = (unsigned)f2bf(x.x) | ((unsigned)f2bf(x.y) << 16);
  r.y = (unsigned)f2bf(x.z) | ((unsigned)f2bf(x.w) << 16);
  r.z = (unsigned)f2bf(y.x) | ((unsigned)f2bf(y.y) << 16);
  r.w = (unsigned)f2bf(y.z) | ((unsigned)f2bf(y.w) << 16);
  ((uint4*)o)[i] = r;
}

// lin_weight (511x256) -> bf16 padded to 512 rows (row 511 zeroed)
__global__ void __launch_bounds__(256) cvt_w(
    const float* __restrict__ src, unsigned short* __restrict__ o) {
  int i  = blockIdx.x * 256 + threadIdx.x;   // 16384 threads, 8 elems each
  int e0 = i * 8;
  int row = e0 >> 8;
  uint4 r = {0u, 0u, 0u, 0u};
  if (row < NC) {
    const float4* v4 = (const float4*)src;
    float4 x = v4[2 * i], y = v4[2 * i + 1];
    r.x = (unsigned)f2bf(x.x) | ((unsigned)f2bf(x.y) << 16);
    r.y = (unsigned)f2bf(x.z) | ((unsigned)f2bf(x.w) << 16);
    r.z = (unsigned)f2bf(y.x) | ((unsigned)f2bf(y.y) << 16);
    r.w = (unsigned)f2bf(y.z) | ((unsigned)f2bf(y.w) << 16);
  }
  ((uint4*)o)[i] = r;
}

// ---------------------------------------------------------------------------
// Phase 3b: out[m][c] = sum_k A[m][k]*W[c][k] + bias[c]   (A: M=130944 x 256,
// W: 512x256 bf16 zero-padded). m97-style: 128x128 tile, BK=64,
// global_load_lds width 16, mfma_f32_16x16x32_bf16, 4 waves x (64x64).
// ---------------------------------------------------------------------------
__global__ void __launch_bounds__(256) gemm_kernel(
    const short* __restrict__ A, const short* __restrict__ W,
    const float* __restrict__ bias, float* __restrict__ out) {
  __shared__ short As[128 * 64];
  __shared__ short Ws[128 * 64];
  int tid  = threadIdx.x;
  int lane = tid & 63;
  int w    = tid >> 6;
  int m0   = blockIdx.x * 128;
  int c0   = blockIdx.y * 128;
  int wm   = (w & 1) * 64;
  int wc   = (w >> 1) * 64;
  int frow = lane & 15;
  int quad = lane >> 4;
  f32x4 acc[4][4];
#pragma unroll
  for (int i = 0; i < 4; ++i)
#pragma unroll
    for (int j = 0; j < 4; ++j) acc[i][j] = (f32x4){0.f, 0.f, 0.f, 0.f};

  for (int k0 = 0; k0 < ND; k0 += 64) {
#pragma unroll
    for (int i = 0; i < 4; ++i) {
      int idx = i * 256 + tid;
      int row = idx >> 3;
      int ch  = idx & 7;
      const short* ga = A + (size_t)(m0 + row) * ND + k0 + ch * 8;
      const short* gw = W + (size_t)(c0 + row) * ND + k0 + ch * 8;
      __builtin_amdgcn_global_load_lds(
          (const __attribute__((address_space(1))) void*)ga,
          (__attribute__((address_space(3))) void*)(As + idx * 8), 16, 0, 0);
      __builtin_amdgcn_global_load_lds(
          (const __attribute__((address_space(1))) void*)gw,
          (__attribute__((address_space(3))) void*)(Ws + idx * 8), 16, 0, 0);
    }
    __syncthreads();   // compiler emits s_waitcnt vmcnt(0) before s_barrier
#pragma unroll
    for (int ks = 0; ks < 2; ++ks) {
      short8 af[4], wf[4];
#pragma unroll
      for (int mi = 0; mi < 4; ++mi)
        af[mi] = *(const short8*)(As + (wm + mi * 16 + frow) * 64 + ks * 32 + quad * 8);
#pragma unroll
      for (int ci = 0; ci < 4; ++ci)
        wf[ci] = *(const short8*)(Ws + (wc + ci * 16 + frow) * 64 + ks * 32 + quad * 8);
#pragma unroll
      for (int mi = 0; mi < 4; ++mi)
#pragma unroll
        for (int ci = 0; ci < 4; ++ci)
          acc[mi][ci] = __builtin_amdgcn_mfma_f32_16x16x32_bf16(
              af[mi], wf[ci], acc[mi][ci], 0, 0, 0);
    }
    __syncthreads();
  }
  // Epilogue: D layout col=lane&15, row=quad*4+r (m89/m91 verified)
#pragma unroll
  for (int mi = 0; mi < 4; ++mi) {
#pragma unroll
    for (int ci = 0; ci < 4; ++ci) {
      int col = c0 + wc + ci * 16 + frow;
      if (col < NC) {
        float bv = bias[col];
#pragma unroll
        for (int r = 0; r < 4; ++r) {
          int m = m0 + wm + mi * 16 + quad * 4 + r;
          out[(size_t)m * NC + col] = acc[mi][ci][r] + bv;
        }
      }
    }
  }
}

// ---------------------------------------------------------------------------
// Workspace layout (requires ws_size >= 201,392,128 bytes):
//   [0)                vec   fp32  B*N*D          = 134,086,656 B
//   [134086656)        vecb  bf16  B*N*D          =  67,043,328 B
//   [201129984)        wb    bf16  512*D          =     262,144 B
// ---------------------------------------------------------------------------
extern "C" void kernel_launch(void* const* d_in, const int* in_sizes, int n_in,
                              void* d_out, int out_size, void* d_ws, size_t ws_size,
                              hipStream_t stream) {
  const int*   lcid  = (const int*)d_in[1];
  const int*   cmask = (const int*)d_in[2];
  const int*   cinfo = (const int*)d_in[3];
  const float* emb   = (const float*)d_in[4];
  const float* lw    = (const float*)d_in[5];
  const float* lb    = (const float*)d_in[6];
  float*       out   = (float*)d_out;

  const size_t vecBytes  = (size_t)NB * NN * ND * 4;   // 134,086,656
  const size_t vecbBytes = (size_t)NB * NN * ND * 2;   //  67,043,328
  float*          vec  = (float*)d_ws;
  unsigned short* vecb = (unsigned short*)((char*)d_ws + vecBytes);
  unsigned short* wb   = (unsigned short*)((char*)d_ws + vecBytes + vecbBytes);

  hipMemsetAsync(vec, 0, vecBytes, stream);
  embed_scatter<<<NB * NL / 4, 256, 0, stream>>>(lcid, cmask, emb, vec);
  cvt_w<<<(512 * ND / 8) / 256, 256, 0, stream>>>(lw, wb);
  compose_kernel<<<NB, 256, 0, stream>>>(cinfo, vec);
  int n8 = NB * NN * ND / 8;
  cvt_vec<<<(n8 + 255) / 256, 256, 0, stream>>>(vec, (unsigned short*)vecb, n8);
  gemm_kernel<<<dim3((NB * NN) / 128, 4), 256, 0, stream>>>(
      (const short*)vecb, (const short*)wb, lb, out);
}

// Round 2
// 679.717 us; speedup vs baseline: 1.4420x; 1.4420x over previous
//
#include <hip/hip_runtime.h>

// Problem constants (match reference setup_inputs)
#define NB 128
#define NL 512
#define NN 1023
#define NT 511
#define ND 256
#define NC 511
#define EPSF 1e-6f

// Source encoding for the renamed dataflow:
//   SRC_ZERO          -> zero vector
//   0..511            -> leaf row r (leafbuf)
//   SLOTC + t         -> output slot of type-2 step t (outbuf)
//   STEPC + t         -> unresolved reference to writer step t (resolution only)
#define SRC_ZERO (-1)
#define SLOTC 4096
#define STEPC 8192

typedef __attribute__((ext_vector_type(8))) short short8;   // 8 x bf16 (4 VGPRs)
typedef __attribute__((ext_vector_type(4))) float f32x4;    // MFMA accumulator

__device__ __forceinline__ unsigned short f2bf(float f) {
  unsigned u = __builtin_bit_cast(unsigned, f);
  u += 0x7FFFu + ((u >> 16) & 1u);   // round-to-nearest-even
  return (unsigned short)(u >> 16);
}

// ---------------------------------------------------------------------------
// Phase 1: normalize embedding rows; write fp32 into leafbuf[b][slot] (compose
// operand source) AND bf16 into vecb[b][slot] (GEMM input). Masked rows are
// written as zeros (slots = arange(L) cover every leaf row exactly once).
// One wave per (b,l) row.
// ---------------------------------------------------------------------------
__global__ void __launch_bounds__(256) embed_scatter(
    const int* __restrict__ lcid, const int* __restrict__ cmask,
    const float* __restrict__ emb, float* __restrict__ leafbuf,
    unsigned short* __restrict__ vecb) {
  int rid  = blockIdx.x * 4 + (threadIdx.x >> 6);   // b*NL + l
  int lane = threadIdx.x & 63;
  int slot = lcid[2 * rid];
  int vid  = lcid[2 * rid + 1];
  int msk  = cmask[rid];
  int b    = rid >> 9;                               // / NL
  float4 v = {0.f, 0.f, 0.f, 0.f};
  if (msk) v = ((const float4*)(emb + (size_t)vid * ND))[lane];
  float ss = v.x * v.x + v.y * v.y + v.z * v.z + v.w * v.w;
#pragma unroll
  for (int off = 32; off > 0; off >>= 1) ss += __shfl_down(ss, off, 64);
  ss = __shfl(ss, 0, 64);
  float inv = 1.0f / (sqrtf(ss) + EPSF);   // msk==0: v=0 -> o=0 (no NaN)
  float4 o;
  o.x = v.x * inv; o.y = v.y * inv; o.z = v.z * inv; o.w = v.w * inv;
  ((float4*)(leafbuf + ((size_t)b * 512 + slot) * ND))[lane] = o;
  unsigned short h0 = f2bf(o.x), h1 = f2bf(o.y), h2 = f2bf(o.z), h3 = f2bf(o.w);
  uint2 pk;
  pk.x = (unsigned)h0 | ((unsigned)h1 << 16);
  pk.y = (unsigned)h2 | ((unsigned)h3 << 16);
  ((uint2*)(vecb + ((size_t)b * NN + slot) * ND))[lane] = pk;
}

// ---------------------------------------------------------------------------
// Phase 2: compose. One block (256 threads) per batch.
//  A) parallel resolution in LDS: last-writer scan, type-1 chain collapse
//     (pointer jumping), zero propagation, backward liveness, compaction.
//  B) sequential execution of the E surviving correlation ops with operand
//     prefetch (+distance-1 patch from registers). Outputs to renamed slots.
//  C) gather: write final parent rows (bf16) into vecb.
// ---------------------------------------------------------------------------
__global__ void __launch_bounds__(256) compose_kernel(
    const int* __restrict__ info, const int* __restrict__ lcid,
    const int* __restrict__ cmask, const float* __restrict__ leafbuf,
    float* __restrict__ outbuf, unsigned short* __restrict__ vecb) {
  const int b    = blockIdx.x;
  const int tid  = threadIdx.x;
  const int lane = tid & 63;
  const int w    = tid >> 6;

  __shared__ int4 sinfo4[NT];                 // (ctype, parent, lchild, rchild)
  __shared__ int lwl[NT], lwr[NT], fwr[NT];   // last writer of lc/rc before t; of row 512+i overall
  __shared__ int ptr_[NT];                    // per-step terminal value (type-1 chains)
  __shared__ int lsA[NT], rsA[NT];            // resolved operands of type-2 steps
  __shared__ int effl[NT], effr[NT], effs[NT];// compacted live op list
  __shared__ int fsrc[NT];                    // final source of parent row 512+i
  __shared__ int offs[NT + 1];                // prefix-sum scratch
  __shared__ unsigned char deadF[NT], liveF[NT], lzero[512];
  __shared__ float a_s[ND], b_s[2 * ND], part[4][ND];
  __shared__ float red[4];
  __shared__ int changed;

  const float* lb = leafbuf + (size_t)b * 512 * ND;
  float*       ob = outbuf + (size_t)b * NT * ND;

  // ---- load step info + leaf-zero mask ----
  const int4* ib4 = (const int4*)(info + (size_t)b * NT * 4);
  for (int t = tid; t < NT; t += 256) sinfo4[t] = ib4[t];
  for (int l = tid; l < 512; l += 256) lzero[l] = 1;   // default: zero row
  __syncthreads();
  for (int l = tid; l < 512; l += 256) {
    int row = lcid[((size_t)b * NL + l) * 2];
    lzero[row] = (cmask[(size_t)b * NL + l] == 0) ? 1 : 0;
  }
  __syncthreads();

  // ---- last-writer scan (broadcast LDS reads, all t in parallel) ----
  const int  t1   = tid;
  const int  t2   = tid + 256;
  const bool has2 = (t2 < NT);
  int4 m1 = sinfo4[t1];
  int4 m2; m2.x = 0; m2.y = 0; m2.z = 0; m2.w = 0;
  if (has2) m2 = sinfo4[t2];
  int l1 = -1, r1 = -1, l2 = -1, r2 = -1, f1 = -1, f2 = -1;
  const int row1 = 512 + t1, row2 = 512 + t2;
  for (int tp = 0; tp < NT; ++tp) {
    int4 wi = sinfo4[tp];
    if (wi.x > 0) {   // type-1/2 write row wi.y (in [512,1023))
      if (tp < t1) { if (wi.y == m1.z) l1 = tp; if (wi.y == m1.w) r1 = tp; }
      if (wi.y == row1) f1 = tp;
      if (has2) {
        if (tp < t2) { if (wi.y == m2.z) l2 = tp; if (wi.y == m2.w) r2 = tp; }
        if (wi.y == row2) f2 = tp;
      }
    }
  }
  lwl[t1] = l1; lwr[t1] = r1; fwr[t1] = f1;
  if (has2) { lwl[t2] = l2; lwr[t2] = r2; fwr[t2] = f2; }
  __syncthreads();

  // ---- type-1 chain collapse via pointer jumping ----
  for (int t = tid; t < NT; t += 256) {
    int4 m = sinfo4[t];
    int v;
    if (m.x == 2) v = SLOTC + t;
    else if (m.x == 1) {
      int lc = m.z;
      if (lc < 512) v = lc;
      else v = (lwl[t] >= 0) ? (STEPC + lwl[t]) : SRC_ZERO;
    } else v = SRC_ZERO;
    ptr_[t] = v;
  }
  __syncthreads();
  for (int it = 0; it < 10; ++it) {   // 2^10 covers any chain length <= 511
    int v1 = ptr_[t1]; if (v1 >= STEPC) v1 = ptr_[v1 - STEPC];
    int v2 = 0;
    if (has2) { v2 = ptr_[t2]; if (v2 >= STEPC) v2 = ptr_[v2 - STEPC]; }
    __syncthreads();
    ptr_[t1] = v1; if (has2) ptr_[t2] = v2;
    __syncthreads();
  }

  // ---- resolve type-2 operands + final row sources ----
  auto normv = [&](int v) -> int {   // masked-out leaf row == zero vector
    if (v >= 0 && v < 512 && lzero[v]) return SRC_ZERO;
    return v;
  };
  auto collapseW = [&](int wstep) -> int {
    int v = (sinfo4[wstep].x == 2) ? (SLOTC + wstep) : ptr_[wstep];
    return normv(v);
  };
  for (int t = tid; t < NT; t += 256) {
    int4 m = sinfo4[t];
    if (m.x == 2) {
      int lc = m.z, rc = m.w;
      int a = (lc < 512) ? normv(lc) : ((lwl[t] >= 0) ? collapseW(lwl[t]) : SRC_ZERO);
      int c = (rc < 512) ? normv(rc) : ((lwr[t] >= 0) ? collapseW(lwr[t]) : SRC_ZERO);
      lsA[t] = a; rsA[t] = c;
      deadF[t] = (a == SRC_ZERO || c == SRC_ZERO) ? 1 : 0;
    } else {
      deadF[t] = 0;
    }
    liveF[t] = 0;
    int fw = fwr[t];
    fsrc[t] = (fw >= 0) ? collapseW(fw) : SRC_ZERO;
  }
  __syncthreads();

  // ---- zero propagation fixpoint (corr with zero operand == exact zero) ----
  for (int rounds = 0; rounds < 600; ++rounds) {
    if (tid == 0) changed = 0;
    __syncthreads();
    for (int t = tid; t < NT; t += 256) {
      if (sinfo4[t].x == 2 && !deadF[t]) {
        int a = lsA[t], c = rsA[t];
        if (a >= SLOTC && deadF[a - SLOTC]) { a = SRC_ZERO; lsA[t] = a; }
        if (c >= SLOTC && deadF[c - SLOTC]) { c = SRC_ZERO; rsA[t] = c; }
        if (a == SRC_ZERO || c == SRC_ZERO) { deadF[t] = 1; changed = 1; }
      }
    }
    __syncthreads();
    if (!changed) break;
    __syncthreads();
  }

  // ---- backward liveness fixpoint (skip ops overwritten before any read) ----
  for (int t = tid; t < NT; t += 256) {
    int f = fsrc[t];
    if (f >= SLOTC && deadF[f - SLOTC]) { f = SRC_ZERO; fsrc[t] = f; }
    if (f >= SLOTC) liveF[f - SLOTC] = 1;
  }
  __syncthreads();
  for (int rounds = 0; rounds < 600; ++rounds) {
    if (tid == 0) changed = 0;
    __syncthreads();
    for (int t = tid; t < NT; t += 256) {
      if (sinfo4[t].x == 2 && liveF[t] && !deadF[t]) {
        int a = lsA[t], c = rsA[t];
        if (a >= SLOTC && !liveF[a - SLOTC]) { liveF[a - SLOTC] = 1; changed = 1; }
        if (c >= SLOTC && !liveF[c - SLOTC]) { liveF[c - SLOTC] = 1; changed = 1; }
      }
    }
    __syncthreads();
    if (!changed) break;
    __syncthreads();
  }

  // ---- compact live ops (order-preserving => operand slots strictly earlier) ----
  for (int t = tid; t < NT + 1; t += 256)
    offs[t] = (t < NT && sinfo4[t].x == 2 && !deadF[t] && liveF[t]) ? 1 : 0;
  __syncthreads();
  for (int k = 1; k < 512; k <<= 1) {
    int v1 = offs[t1], u1 = (t1 >= k) ? offs[t1 - k] : 0;
    int v2 = offs[t2], u2 = (t2 >= k) ? offs[t2 - k] : 0;
    __syncthreads();
    offs[t1] = v1 + u1; offs[t2] = v2 + u2;
    __syncthreads();
  }
  for (int t = tid; t < NT; t += 256) {
    if (sinfo4[t].x == 2 && !deadF[t] && liveF[t]) {
      int pos = offs[t] - 1;
      effl[pos] = lsA[t]; effr[pos] = rsA[t]; effs[pos] = t;
    }
  }
  __syncthreads();
  const int E = offs[NT - 1];

  // ---- sequential execution with operand prefetch ----
  auto loadsrc = [&](int s) -> float {
    if (s < 0) return 0.f;
    if (s < 512) return lb[(size_t)s * ND + tid];
    return ob[(size_t)(s - SLOTC) * ND + tid];
  };
  if (E > 0) {
    float a0 = loadsrc(effl[0]);
    float b0 = loadsrc(effr[0]);
    a_s[tid] = a0; b_s[tid] = b0; b_s[ND + tid] = b0;
  }
  __syncthreads();
  for (int e = 0; e < E; ++e) {
    bool more = (e + 1 < E);
    bool depL = false, depR = false;
    float pa = 0.f, pb = 0.f;
    if (more) {   // prefetch next operands; patch distance-1 deps from regs
      int curS = SLOTC + effs[e];
      int nls = effl[e + 1], nrs = effr[e + 1];
      if (nls == curS) depL = true; else pa = loadsrc(nls);
      if (nrs == curS) depR = true; else pb = loadsrc(nrs);
    }
    // circular correlation c[k] = sum_j a[j] * b[(j+k) & 255]
    const float4* a4 = (const float4*)a_s;
    const float4* b4 = (const float4*)b_s;
    float c0 = 0.f, c1 = 0.f, c2 = 0.f, c3 = 0.f;
    int base = 16 * w + lane;
    float4 B0 = b4[base];
#pragma unroll
    for (int i = 0; i < 16; ++i) {
      float4 A  = a4[16 * w + i];        // uniform -> LDS broadcast
      float4 B1 = b4[base + i + 1];      // rolling window
      c0 += A.x * B0.x + A.y * B0.y + A.z * B0.z + A.w * B0.w;
      c1 += A.x * B0.y + A.y * B0.z + A.z * B0.w + A.w * B1.x;
      c2 += A.x * B0.z + A.y * B0.w + A.z * B1.x + A.w * B1.y;
      c3 += A.x * B0.w + A.y * B1.x + A.z * B1.y + A.w * B1.z;
      B0 = B1;
    }
    float4 pc; pc.x = c0; pc.y = c1; pc.z = c2; pc.w = c3;
    ((float4*)part[w])[lane] = pc;
    __syncthreads();                                   // B1: compute done
    float c = part[0][tid] + part[1][tid] + part[2][tid] + part[3][tid];
    float ss = c * c;
#pragma unroll
    for (int off = 32; off > 0; off >>= 1) ss += __shfl_down(ss, off, 64);
    if (lane == 0) red[w] = ss;
    __syncthreads();                                   // B2: norm partials ready
    float tot = red[0] + red[1] + red[2] + red[3];
    float res = c * (1.f / (sqrtf(tot) + EPSF));
    ob[(size_t)effs[e] * ND + tid] = res;              // renamed slot write
    if (more) {
      a_s[tid] = depL ? res : pa;
      float bv = depR ? res : pb;
      b_s[tid] = bv; b_s[ND + tid] = bv;
    }
    __syncthreads();   // B3: staging ready; drains slot store (vmcnt) for e+2 prefetch
  }

  // ---- gather: final parent rows -> vecb (bf16) ----
  __syncthreads();
  unsigned short* vb = vecb + ((size_t)b * NN + 512) * ND;
#pragma unroll 4
  for (int idx = 0; idx < NT; ++idx) {
    int s = fsrc[idx];
    float v = 0.f;
    if (s >= 0)
      v = (s < 512) ? lb[(size_t)s * ND + tid] : ob[(size_t)(s - SLOTC) * ND + tid];
    vb[(size_t)idx * ND + tid] = f2bf(v);
  }
}

// ---------------------------------------------------------------------------
// lin_weight (511x256) -> bf16 padded to 512 rows (row 511 zeroed)
// ---------------------------------------------------------------------------
__global__ void __launch_bounds__(256) cvt_w(
    const float* __restrict__ src, unsigned short* __restrict__ o) {
  int i   = blockIdx.x * 256 + threadIdx.x;   // 16384 threads, 8 elems each
  int row = (i * 8) >> 8;
  uint4 r = {0u, 0u, 0u, 0u};
  if (row < NC) {
    const float4* v4 = (const float4*)src;
    float4 x = v4[2 * i], y = v4[2 * i + 1];
    r.x = (unsigned)f2bf(x.x) | ((unsigned)f2bf(x.y) << 16);
    r.y = (unsigned)f2bf(x.z) | ((unsigned)f2bf(x.w) << 16);
    r.z = (unsigned)f2bf(y.x) | ((unsigned)f2bf(y.y) << 16);
    r.w = (unsigned)f2bf(y.z) | ((unsigned)f2bf(y.w) << 16);
  }
  ((uint4*)o)[i] = r;
}

// ---------------------------------------------------------------------------
// Phase 3: out[m][c] = sum_k A[m][k]*W[c][k] + bias[c]  (A: 130944x256 bf16,
// W: 512x256 bf16 zero-padded). m97-style: 128x128 tile, BK=64,
// global_load_lds width 16, mfma_f32_16x16x32_bf16, 4 waves x (64x64).
// ---------------------------------------------------------------------------
__global__ void __launch_bounds__(256) gemm_kernel(
    const short* __restrict__ A, const short* __restrict__ W,
    const float* __restrict__ bias, float* __restrict__ out) {
  __shared__ short As[128 * 64];
  __shared__ short Ws[128 * 64];
  int tid  = threadIdx.x;
  int lane = tid & 63;
  int w    = tid >> 6;
  int m0   = blockIdx.x * 128;
  int c0   = blockIdx.y * 128;
  int wm   = (w & 1) * 64;
  int wc   = (w >> 1) * 64;
  int frow = lane & 15;
  int quad = lane >> 4;
  f32x4 acc[4][4];
#pragma unroll
  for (int i = 0; i < 4; ++i)
#pragma unroll
    for (int j = 0; j < 4; ++j) acc[i][j] = (f32x4){0.f, 0.f, 0.f, 0.f};

  for (int k0 = 0; k0 < ND; k0 += 64) {
#pragma unroll
    for (int i = 0; i < 4; ++i) {
      int idx = i * 256 + tid;
      int row = idx >> 3;
      int ch  = idx & 7;
      const short* ga = A + (size_t)(m0 + row) * ND + k0 + ch * 8;
      const short* gw = W + (size_t)(c0 + row) * ND + k0 + ch * 8;
      __builtin_amdgcn_global_load_lds(
          (const __attribute__((address_space(1))) void*)ga,
          (__attribute__((address_space(3))) void*)(As + idx * 8), 16, 0, 0);
      __builtin_amdgcn_global_load_lds(
          (const __attribute__((address_space(1))) void*)gw,
          (__attribute__((address_space(3))) void*)(Ws + idx * 8), 16, 0, 0);
    }
    __syncthreads();
#pragma unroll
    for (int ks = 0; ks < 2; ++ks) {
      short8 af[4], wf[4];
#pragma unroll
      for (int mi = 0; mi < 4; ++mi)
        af[mi] = *(const short8*)(As + (wm + mi * 16 + frow) * 64 + ks * 32 + quad * 8);
#pragma unroll
      for (int ci = 0; ci < 4; ++ci)
        wf[ci] = *(const short8*)(Ws + (wc + ci * 16 + frow) * 64 + ks * 32 + quad * 8);
#pragma unroll
      for (int mi = 0; mi < 4; ++mi)
#pragma unroll
        for (int ci = 0; ci < 4; ++ci)
          acc[mi][ci] = __builtin_amdgcn_mfma_f32_16x16x32_bf16(
              af[mi], wf[ci], acc[mi][ci], 0, 0, 0);
    }
    __syncthreads();
  }
#pragma unroll
  for (int mi = 0; mi < 4; ++mi) {
#pragma unroll
    for (int ci = 0; ci < 4; ++ci) {
      int col = c0 + wc + ci * 16 + frow;
      if (col < NC) {
        float bv = bias[col];
#pragma unroll
        for (int r = 0; r < 4; ++r) {
          int m = m0 + wm + mi * 16 + quad * 4 + r;
          out[(size_t)m * NC + col] = acc[mi][ci][r] + bv;
        }
      }
    }
  }
}

// ---------------------------------------------------------------------------
// Workspace layout (201,392,128 bytes total — identical to round-1 footprint):
//   [0)           leafbuf fp32 [B][512][D]  =  67,108,864 B
//   [67108864)    outbuf  fp32 [B][511][D]  =  66,977,792 B
//   [134086656)   vecb    bf16 [B][1023][D] =  67,043,328 B
//   [201129984)   wb      bf16 [512][D]     =     262,144 B
// No memsets needed: every byte read is written first.
// ---------------------------------------------------------------------------
extern "C" void kernel_launch(void* const* d_in, const int* in_sizes, int n_in,
                              void* d_out, int out_size, void* d_ws, size_t ws_size,
                              hipStream_t stream) {
  const int*   lcid  = (const int*)d_in[1];
  const int*   cmask = (const int*)d_in[2];
  const int*   cinfo = (const int*)d_in[3];
  const float* emb   = (const float*)d_in[4];
  const float* lw    = (const float*)d_in[5];
  const float* lb    = (const float*)d_in[6];
  float*       out   = (float*)d_out;

  char* ws = (char*)d_ws;
  float*          leafbuf = (float*)ws;
  float*          outbuf  = (float*)(ws + 67108864);
  unsigned short* vecb    = (unsigned short*)(ws + 134086656);
  unsigned short* wb      = (unsigned short*)(ws + 201129984);

  embed_scatter<<<NB * NL / 4, 256, 0, stream>>>(lcid, cmask, emb, leafbuf, vecb);
  cvt_w<<<(512 * ND / 8) / 256, 256, 0, stream>>>(lw, wb);
  compose_kernel<<<NB, 256, 0, stream>>>(cinfo, lcid, cmask, leafbuf, outbuf, vecb);
  gemm_kernel<<<dim3((NB * NN) / 128, 4), 256, 0, stream>>>(
      (const short*)vecb, (const short*)wb, lb, out);
}

// Round 3
// 554.959 us; speedup vs baseline: 1.7662x; 1.2248x over previous
//
#include <hip/hip_runtime.h>

// Problem constants (match reference setup_inputs)
#define NB 128
#define NL 512
#define NN 1023
#define NT 511
#define ND 256
#define NC 511
#define EPSF 1e-6f

// Source encoding for the renamed dataflow:
//   SRC_ZERO          -> zero vector
//   0..511            -> leaf row r (leafbuf)
//   SLOTC + t         -> output slot of type-2 step t (outbuf)
//   STEPC + t         -> unresolved reference to writer step t (resolution only)
#define SRC_ZERO (-1)
#define SLOTC 4096
#define STEPC 8192

typedef __attribute__((ext_vector_type(8))) short short8;   // 8 x bf16 (4 VGPRs)
typedef __attribute__((ext_vector_type(4))) float f32x4;    // MFMA accumulator

__device__ __forceinline__ unsigned short f2bf(float f) {
  unsigned u = __builtin_bit_cast(unsigned, f);
  u += 0x7FFFu + ((u >> 16) & 1u);   // round-to-nearest-even
  return (unsigned short)(u >> 16);
}

// ---------------------------------------------------------------------------
// Phase 1: normalize embedding rows; fp32 -> leafbuf[b][slot], bf16 -> vecb.
// One wave per (b,l) row; slots are arange(L) so rows 0..511 fully covered.
// ---------------------------------------------------------------------------
__global__ void __launch_bounds__(256) embed_scatter(
    const int* __restrict__ lcid, const int* __restrict__ cmask,
    const float* __restrict__ emb, float* __restrict__ leafbuf,
    unsigned short* __restrict__ vecb) {
  int rid  = blockIdx.x * 4 + (threadIdx.x >> 6);   // b*NL + l
  int lane = threadIdx.x & 63;
  int slot = lcid[2 * rid];
  int vid  = lcid[2 * rid + 1];
  int msk  = cmask[rid];
  int b    = rid >> 9;                               // / NL
  float4 v = {0.f, 0.f, 0.f, 0.f};
  if (msk) v = ((const float4*)(emb + (size_t)vid * ND))[lane];
  float ss = v.x * v.x + v.y * v.y + v.z * v.z + v.w * v.w;
#pragma unroll
  for (int off = 32; off > 0; off >>= 1) ss += __shfl_down(ss, off, 64);
  ss = __shfl(ss, 0, 64);
  float inv = 1.0f / (sqrtf(ss) + EPSF);   // msk==0: v=0 -> o=0 (no NaN)
  float4 o;
  o.x = v.x * inv; o.y = v.y * inv; o.z = v.z * inv; o.w = v.w * inv;
  ((float4*)(leafbuf + ((size_t)b * 512 + slot) * ND))[lane] = o;
  uint2 pk;
  pk.x = (unsigned)f2bf(o.x) | ((unsigned)f2bf(o.y) << 16);
  pk.y = (unsigned)f2bf(o.z) | ((unsigned)f2bf(o.w) << 16);
  ((uint2*)(vecb + ((size_t)b * NN + slot) * ND))[lane] = pk;
}

// ---------------------------------------------------------------------------
// Phase 2: compose. One block (1024 threads = 16 waves) per batch.
//  A) resolution in LDS: last-writer scan, type-1 chain collapse, zero
//     propagation, backward liveness, ASAP levels, level-bucketed schedule.
//  B) level-parallel execution: one op per wave, 16 ops per phase, ONE
//     __syncthreads per level. Operand traffic via same-XCD L2.
//  C) fsrc -> global (staged in d_out; gemm overwrites it later).
// ---------------------------------------------------------------------------
__global__ void __launch_bounds__(1024) compose_kernel(
    const int* __restrict__ info, const int* __restrict__ lcid,
    const int* __restrict__ cmask, const float* __restrict__ leafbuf,
    float* __restrict__ outbuf, int* __restrict__ fsrcG) {
  const int b    = blockIdx.x;
  const int tid  = threadIdx.x;
  const int lane = tid & 63;
  const int wav  = tid >> 6;

  __shared__ int4 sinfo4[NT];                 // (ctype, parent, lchild, rchild)
  __shared__ int lwl[NT], lwr[NT], fwr[NT];   // last writers
  __shared__ int ptr_[NT];                    // type-1 chain terminal
  __shared__ int lsA[NT], rsA[NT];            // resolved type-2 operands
  __shared__ int lvl[NT], fsrc[NT];
  __shared__ int schedS[NT], schedL[NT], schedR[NT];
  __shared__ int offs[512], cnt[512], cnt2[512];
  __shared__ unsigned char deadF[NT], liveF[NT], lzero[512];
  __shared__ float a_st[16][256], b_st[16][512];
  __shared__ int changed, smax;

  const float* lb = leafbuf + (size_t)b * 512 * ND;
  float*       ob = outbuf + (size_t)b * NT * ND;

  // ---- load step info + leaf-zero mask ----
  const int4* ib4 = (const int4*)(info + (size_t)b * NT * 4);
  for (int i = tid; i < NT; i += 1024) sinfo4[i] = ib4[i];
  if (tid < 512) lzero[tid] = 1;
  if (tid == 0) smax = 0;
  __syncthreads();
  if (tid < NL) {
    int row = lcid[((size_t)b * NL + tid) * 2];   // slots unique per batch
    lzero[row] = (cmask[(size_t)b * NL + tid] == 0) ? 1 : 0;
  }
  __syncthreads();

  // ---- last-writer scan (broadcast reads; one thread per step) ----
  const int t = tid;
  int4 m1 = {0, 0, 0, 0};
  if (t < NT) m1 = sinfo4[t];
  int l1 = -1, r1 = -1, f1 = -1;
  const int prow = 512 + t;
  for (int tp = 0; tp < NT; ++tp) {
    int4 wi = sinfo4[tp];
    if (wi.x > 0) {   // type-1/2 write row wi.y (in [512,1023))
      if (t < NT && tp < t) { if (wi.y == m1.z) l1 = tp; if (wi.y == m1.w) r1 = tp; }
      if (wi.y == prow) f1 = tp;
    }
  }
  if (t < NT) { lwl[t] = l1; lwr[t] = r1; fwr[t] = f1; }
  __syncthreads();

  // ---- type-1 chain collapse via pointer jumping ----
  if (t < NT) {
    int v;
    if (m1.x == 2) v = SLOTC + t;
    else if (m1.x == 1) {
      if (m1.z < 512) v = m1.z;
      else v = (l1 >= 0) ? (STEPC + l1) : SRC_ZERO;
    } else v = SRC_ZERO;
    ptr_[t] = v;
  }
  __syncthreads();
  for (int it = 0; it < 10; ++it) {   // 2^10 covers any chain length <= 511
    int v = 0;
    if (t < NT) { v = ptr_[t]; if (v >= STEPC) v = ptr_[v - STEPC]; }
    __syncthreads();
    if (t < NT) ptr_[t] = v;
    __syncthreads();
  }

  // ---- resolve type-2 operands + final row sources ----
  auto normv = [&](int v) -> int {   // masked-out leaf row == zero vector
    if (v >= 0 && v < 512 && lzero[v]) return SRC_ZERO;
    return v;
  };
  auto collapseW = [&](int wstep) -> int {
    int v = (sinfo4[wstep].x == 2) ? (SLOTC + wstep) : ptr_[wstep];
    return normv(v);
  };
  if (t < NT) {
    if (m1.x == 2) {
      int a = (m1.z < 512) ? normv(m1.z) : ((l1 >= 0) ? collapseW(l1) : SRC_ZERO);
      int c = (m1.w < 512) ? normv(m1.w) : ((r1 >= 0) ? collapseW(r1) : SRC_ZERO);
      lsA[t] = a; rsA[t] = c;
      deadF[t] = (a == SRC_ZERO || c == SRC_ZERO) ? 1 : 0;
    } else {
      deadF[t] = 0;
    }
    liveF[t] = 0;
    fsrc[t] = (f1 >= 0) ? collapseW(f1) : SRC_ZERO;
  }
  __syncthreads();

  // ---- zero propagation fixpoint (corr with zero operand == exact zero) ----
  for (int rounds = 0; rounds < NT; ++rounds) {
    if (tid == 0) changed = 0;
    __syncthreads();
    if (t < NT && m1.x == 2 && !deadF[t]) {
      int a = lsA[t], c = rsA[t];
      if (a >= SLOTC && deadF[a - SLOTC]) { a = SRC_ZERO; lsA[t] = a; }
      if (c >= SLOTC && deadF[c - SLOTC]) { c = SRC_ZERO; rsA[t] = c; }
      if (a == SRC_ZERO || c == SRC_ZERO) { deadF[t] = 1; changed = 1; }
    }
    __syncthreads();
    if (!changed) break;
    __syncthreads();
  }

  // ---- backward liveness (skip ops whose output is never read) ----
  if (t < NT) {
    int f = fsrc[t];
    if (f >= SLOTC && deadF[f - SLOTC]) { f = SRC_ZERO; fsrc[t] = f; }
    if (f >= SLOTC) liveF[f - SLOTC] = 1;
  }
  __syncthreads();
  for (int rounds = 0; rounds < NT; ++rounds) {
    if (tid == 0) changed = 0;
    __syncthreads();
    if (t < NT && m1.x == 2 && liveF[t] && !deadF[t]) {
      int a = lsA[t], c = rsA[t];
      if (a >= SLOTC && !liveF[a - SLOTC]) { liveF[a - SLOTC] = 1; changed = 1; }
      if (c >= SLOTC && !liveF[c - SLOTC]) { liveF[c - SLOTC] = 1; changed = 1; }
    }
    __syncthreads();
    if (!changed) break;
    __syncthreads();
  }

  const bool isLive = (t < NT && m1.x == 2 && liveF[t] && !deadF[t]);

  // ---- ASAP levels via monotone fixpoint ----
  if (t < NT) lvl[t] = 0;
  __syncthreads();
  for (int rounds = 0; rounds < NT; ++rounds) {
    if (tid == 0) changed = 0;
    __syncthreads();
    if (isLive) {
      int nl = 1, a = lsA[t], c = rsA[t];
      if (a >= SLOTC) { int dl = lvl[a - SLOTC] + 1; if (dl > nl) nl = dl; }
      if (c >= SLOTC) { int dl = lvl[c - SLOTC] + 1; if (dl > nl) nl = dl; }
      if (nl > lvl[t]) { lvl[t] = nl; changed = 1; }
    }
    __syncthreads();
    if (!changed) break;
    __syncthreads();
  }
  if (isLive) atomicMax(&smax, lvl[t]);

  // ---- bucket ops by level ----
  if (tid < 512) { cnt[tid] = 0; cnt2[tid] = 0; }
  __syncthreads();
  if (isLive) atomicAdd(&cnt[lvl[t]], 1);
  __syncthreads();
  if (tid < 512) offs[tid] = cnt[tid];
  __syncthreads();
  for (int k = 1; k < 512; k <<= 1) {   // inclusive prefix over levels
    int v = 0;
    if (tid < 512) { v = offs[tid]; if (tid >= k) v += offs[tid - k]; }
    __syncthreads();
    if (tid < 512) offs[tid] = v;
    __syncthreads();
  }
  if (isLive) {
    int d = lvl[t];
    int pos = offs[d - 1] + atomicAdd(&cnt2[d], 1);   // d>=1 always
    schedS[pos] = t; schedL[pos] = lsA[t]; schedR[pos] = rsA[t];
  }
  __syncthreads();

  // ---- level-parallel execution: one op per wave ----
  const int maxd = smax;
  for (int d = 1; d <= maxd; ++d) {
    const int base = offs[d - 1];
    const int nops = cnt[d];
    const int nch  = (nops + 15) >> 4;
    for (int ch = 0; ch < nch; ++ch) {
      int rel = ch * 16 + wav;
      if (rel < nops) {           // wave-uniform predicate (depends on wav only)
        int my = base + rel;
        int tt = schedS[my], ls = schedL[my], rs = schedR[my];
        const float* pa = (ls < 512) ? lb + (size_t)ls * ND
                                     : ob + (size_t)(ls - SLOTC) * ND;
        const float* pb = (rs < 512) ? lb + (size_t)rs * ND
                                     : ob + (size_t)(rs - SLOTC) * ND;
        float4 av = ((const float4*)pa)[lane];
        float4 bv = ((const float4*)pb)[lane];
        ((float4*)a_st[wav])[lane] = av;
        ((float4*)b_st[wav])[lane]      = bv;
        ((float4*)b_st[wav])[lane + 64] = bv;   // doubled for mod-256 window
        const float4* a4 = (const float4*)a_st[wav];
        const float4* b4 = (const float4*)b_st[wav];
        // c[4*lane+r] = sum_j a[j] * b[(j + 4*lane + r) & 255]
        float c0 = 0.f, c1 = 0.f, c2 = 0.f, c3 = 0.f;
        float4 B0 = b4[lane];
#pragma unroll 8
        for (int i = 0; i < 64; ++i) {
          float4 A  = a4[i];             // uniform -> LDS broadcast
          float4 B1 = b4[lane + i + 1];  // rolling window (stride-16B, conflict-free)
          c0 += A.x * B0.x + A.y * B0.y + A.z * B0.z + A.w * B0.w;
          c1 += A.x * B0.y + A.y * B0.z + A.z * B0.w + A.w * B1.x;
          c2 += A.x * B0.z + A.y * B0.w + A.z * B1.x + A.w * B1.y;
          c3 += A.x * B0.w + A.y * B1.x + A.z * B1.y + A.w * B1.z;
          B0 = B1;
        }
        float ss = c0 * c0 + c1 * c1 + c2 * c2 + c3 * c3;
#pragma unroll
        for (int off = 32; off > 0; off >>= 1) ss += __shfl_down(ss, off, 64);
        ss = __shfl(ss, 0, 64);
        float inv = 1.f / (sqrtf(ss) + EPSF);
        float4 res;
        res.x = c0 * inv; res.y = c1 * inv; res.z = c2 * inv; res.w = c3 * inv;
        ((float4*)(ob + (size_t)tt * ND))[lane] = res;
      }
      // no intra-level barrier: staging is wave-private, deps are cross-level
    }
    __syncthreads();   // level boundary: drains stores; next level reads hit L2
  }

  // ---- export final-row sources for the gather kernel ----
  for (int i = tid; i < NT; i += 1024) fsrcG[b * NT + i] = fsrc[i];
}

// ---------------------------------------------------------------------------
// Phase 2b: full-grid gather of parent rows -> vecb (bf16). One wave per row.
// ---------------------------------------------------------------------------
__global__ void __launch_bounds__(256) gather_rows(
    const int* __restrict__ fsrcG, const float* __restrict__ leafbuf,
    const float* __restrict__ outbuf, unsigned short* __restrict__ vecb) {
  int rid  = blockIdx.x * 4 + (threadIdx.x >> 6);   // b*NT + idx  (exact grid)
  int lane = threadIdx.x & 63;
  int b    = rid / NT;
  int idx  = rid - b * NT;
  int s    = fsrcG[rid];
  float4 v = {0.f, 0.f, 0.f, 0.f};
  if (s >= 0) {
    const float* src = (s < 512)
        ? (leafbuf + ((size_t)b * 512 + s) * ND)
        : (outbuf + ((size_t)b * NT + (s - SLOTC)) * ND);
    v = ((const float4*)src)[lane];
  }
  uint2 pk;
  pk.x = (unsigned)f2bf(v.x) | ((unsigned)f2bf(v.y) << 16);
  pk.y = (unsigned)f2bf(v.z) | ((unsigned)f2bf(v.w) << 16);
  ((uint2*)(vecb + ((size_t)b * NN + 512 + idx) * ND))[lane] = pk;
}

// ---------------------------------------------------------------------------
// lin_weight (511x256) -> bf16 padded to 512 rows (row 511 zeroed)
// ---------------------------------------------------------------------------
__global__ void __launch_bounds__(256) cvt_w(
    const float* __restrict__ src, unsigned short* __restrict__ o) {
  int i   = blockIdx.x * 256 + threadIdx.x;   // 16384 threads, 8 elems each
  int row = (i * 8) >> 8;
  uint4 r = {0u, 0u, 0u, 0u};
  if (row < NC) {
    const float4* v4 = (const float4*)src;
    float4 x = v4[2 * i], y = v4[2 * i + 1];
    r.x = (unsigned)f2bf(x.x) | ((unsigned)f2bf(x.y) << 16);
    r.y = (unsigned)f2bf(x.z) | ((unsigned)f2bf(x.w) << 16);
    r.z = (unsigned)f2bf(y.x) | ((unsigned)f2bf(y.y) << 16);
    r.w = (unsigned)f2bf(y.z) | ((unsigned)f2bf(y.w) << 16);
  }
  ((uint4*)o)[i] = r;
}

// ---------------------------------------------------------------------------
// Phase 3: out[m][c] = sum_k A[m][k]*W[c][k] + bias[c]  (A: 130944x256 bf16,
// W: 512x256 bf16 zero-padded). 128x128 tile, BK=64, global_load_lds w=16,
// mfma_f32_16x16x32_bf16. Grid (4, 1023): the 4 col-blocks sharing an A-tile
// are dispatch-adjacent -> A served from L2, fetched from HBM once.
// ---------------------------------------------------------------------------
__global__ void __launch_bounds__(256) gemm_kernel(
    const short* __restrict__ A, const short* __restrict__ W,
    const float* __restrict__ bias, float* __restrict__ out) {
  __shared__ short As[128 * 64];
  __shared__ short Ws[128 * 64];
  int tid  = threadIdx.x;
  int lane = tid & 63;
  int w    = tid >> 6;
  int c0   = blockIdx.x * 128;
  int m0   = blockIdx.y * 128;
  int wm   = (w & 1) * 64;
  int wc   = (w >> 1) * 64;
  int frow = lane & 15;
  int quad = lane >> 4;
  f32x4 acc[4][4];
#pragma unroll
  for (int i = 0; i < 4; ++i)
#pragma unroll
    for (int j = 0; j < 4; ++j) acc[i][j] = (f32x4){0.f, 0.f, 0.f, 0.f};

  for (int k0 = 0; k0 < ND; k0 += 64) {
#pragma unroll
    for (int i = 0; i < 4; ++i) {
      int idx = i * 256 + tid;
      int row = idx >> 3;
      int ch  = idx & 7;
      const short* ga = A + (size_t)(m0 + row) * ND + k0 + ch * 8;
      const short* gw = W + (size_t)(c0 + row) * ND + k0 + ch * 8;
      __builtin_amdgcn_global_load_lds(
          (const __attribute__((address_space(1))) void*)ga,
          (__attribute__((address_space(3))) void*)(As + idx * 8), 16, 0, 0);
      __builtin_amdgcn_global_load_lds(
          (const __attribute__((address_space(1))) void*)gw,
          (__attribute__((address_space(3))) void*)(Ws + idx * 8), 16, 0, 0);
    }
    __syncthreads();
#pragma unroll
    for (int ks = 0; ks < 2; ++ks) {
      short8 af[4], wf[4];
#pragma unroll
      for (int mi = 0; mi < 4; ++mi)
        af[mi] = *(const short8*)(As + (wm + mi * 16 + frow) * 64 + ks * 32 + quad * 8);
#pragma unroll
      for (int ci = 0; ci < 4; ++ci)
        wf[ci] = *(const short8*)(Ws + (wc + ci * 16 + frow) * 64 + ks * 32 + quad * 8);
#pragma unroll
      for (int mi = 0; mi < 4; ++mi)
#pragma unroll
        for (int ci = 0; ci < 4; ++ci)
          acc[mi][ci] = __builtin_amdgcn_mfma_f32_16x16x32_bf16(
              af[mi], wf[ci], acc[mi][ci], 0, 0, 0);
    }
    __syncthreads();
  }
#pragma unroll
  for (int mi = 0; mi < 4; ++mi) {
#pragma unroll
    for (int ci = 0; ci < 4; ++ci) {
      int col = c0 + wc + ci * 16 + frow;
      if (col < NC) {
        float bv = bias[col];
#pragma unroll
        for (int r = 0; r < 4; ++r) {
          int m = m0 + wm + mi * 16 + quad * 4 + r;
          out[(size_t)m * NC + col] = acc[mi][ci][r] + bv;
        }
      }
    }
  }
}

// ---------------------------------------------------------------------------
// Workspace layout (201,392,128 bytes — same footprint as round 1/2):
//   [0)           leafbuf fp32 [B][512][D]  =  67,108,864 B
//   [67108864)    outbuf  fp32 [B][511][D]  =  66,977,792 B
//   [134086656)   vecb    bf16 [B][1023][D] =  67,043,328 B
//   [201129984)   wb      bf16 [512][D]     =     262,144 B
// fsrc (128*511 ints) is staged in d_out, which gemm fully overwrites later.
// ---------------------------------------------------------------------------
extern "C" void kernel_launch(void* const* d_in, const int* in_sizes, int n_in,
                              void* d_out, int out_size, void* d_ws, size_t ws_size,
                              hipStream_t stream) {
  const int*   lcid  = (const int*)d_in[1];
  const int*   cmask = (const int*)d_in[2];
  const int*   cinfo = (const int*)d_in[3];
  const float* emb   = (const float*)d_in[4];
  const float* lw    = (const float*)d_in[5];
  const float* lb    = (const float*)d_in[6];
  float*       out   = (float*)d_out;

  char* ws = (char*)d_ws;
  float*          leafbuf = (float*)ws;
  float*          outbuf  = (float*)(ws + 67108864);
  unsigned short* vecb    = (unsigned short*)(ws + 134086656);
  unsigned short* wb      = (unsigned short*)(ws + 201129984);
  int*            fsrcG   = (int*)d_out;   // staged; gemm overwrites all of d_out

  embed_scatter<<<NB * NL / 4, 256, 0, stream>>>(lcid, cmask, emb, leafbuf, vecb);
  cvt_w<<<(512 * ND / 8) / 256, 256, 0, stream>>>(lw, wb);
  compose_kernel<<<NB, 1024, 0, stream>>>(cinfo, lcid, cmask, leafbuf, outbuf, fsrcG);
  gather_rows<<<NB * NT / 4, 256, 0, stream>>>(fsrcG, leafbuf, outbuf, vecb);
  gemm_kernel<<<dim3(4, 1023), 256, 0, stream>>>(
      (const short*)vecb, (const short*)wb, lb, out);
}